// Round 2
// baseline (1594.759 us; speedup 1.0000x reference)
//
#include <hip/hip_runtime.h>

// HGRN BitMLP (all I/O float32):
//   x[8192,2048] -> bitlinear(w_gate[16384,2048]) -> silu(gate)*v
//   -> bitlinear(w_down[2048,8192]) -> out[8192,2048]
// Int8 activations / ternary weights make both GEMMs exact in bf16 MFMA
// (small-integer values are exact in bf16; fp32 accum < 2^24 stays exact).

using short8  = __attribute__((ext_vector_type(8))) short;
using ushort8 = __attribute__((ext_vector_type(8))) unsigned short;
using floatx4 = __attribute__((ext_vector_type(4))) float;

__device__ __forceinline__ float b2f(unsigned short u) {
  return __uint_as_float(((unsigned int)u) << 16);
}
__device__ __forceinline__ unsigned short f2b(float f) {
  unsigned int x = __float_as_uint(f);
  return (unsigned short)((x + 0x7FFFu + ((x >> 16) & 1u)) >> 16);
}
// async global->LDS, 16B per lane; LDS dest = wave-uniform base + lane*16
__device__ __forceinline__ void glds16(const void* g, void* l) {
  __builtin_amdgcn_global_load_lds((const __attribute__((address_space(1))) void*)g,
                                   (__attribute__((address_space(3))) void*)l, 16, 0, 0);
}

// ---------------- deterministic sum(|w|) reduction (f32 input) ----------------
__global__ __launch_bounds__(256) void reduce_abs_kernel(
    const float4* __restrict__ w, float* __restrict__ partials, int n4) {
  int t = threadIdx.x;
  int gid = blockIdx.x * 256 + t;
  int stride = gridDim.x * 256;
  float s = 0.f;
  for (int i = gid; i < n4; i += stride) {
    float4 u = w[i];
    s += fabsf(u.x) + fabsf(u.y) + fabsf(u.z) + fabsf(u.w);
  }
  __shared__ float sm[256];
  sm[t] = s; __syncthreads();
  for (int off = 128; off > 0; off >>= 1) {
    if (t < off) sm[t] += sm[t + off];
    __syncthreads();
  }
  if (t == 0) partials[blockIdx.x] = sm[0];
}

__global__ __launch_bounds__(256) void finalize_kernel(
    const float* __restrict__ pf, float* __restrict__ scales) {
  __shared__ float sm[256];
  int t = threadIdx.x;
  float s = pf[t] + pf[t + 256] + pf[t + 512] + pf[t + 768];
  sm[t] = s; __syncthreads();
  for (int off = 128; off > 0; off >>= 1) {
    if (t < off) sm[t] += sm[t + off];
    __syncthreads();
  }
  if (t == 0) {  // w_gate: 16384*2048 elements
    float c = fmaxf(sm[0] / 33554432.0f, 1e-5f);
    scales[0] = c; scales[2] = 1.0f / c;
  }
  __syncthreads();
  s = pf[1024 + t] + pf[1280 + t] + pf[1536 + t] + pf[1792 + t];
  sm[t] = s; __syncthreads();
  for (int off = 128; off > 0; off >>= 1) {
    if (t < off) sm[t] += sm[t + off];
    __syncthreads();
  }
  if (t == 0) {  // w_down: 2048*8192 elements
    float c = fmaxf(sm[0] / 16777216.0f, 1e-5f);
    scales[1] = c; scales[3] = 1.0f / c;
  }
}

// ------- ternary weight quant: f32 in -> {-1,0,1} stored as bf16 --------
__global__ __launch_bounds__(256) void quant_weight_kernel(
    const float4* __restrict__ w, ushort8* __restrict__ wq,
    const float* __restrict__ invp, int n8) {
  float inv = *invp;  // 1/clip(mean|w|,1e-5)
  int stride = gridDim.x * 256;
  for (int i = blockIdx.x * 256 + threadIdx.x; i < n8; i += stride) {
    float4 a = w[2 * i], b = w[2 * i + 1];
    float v[8] = {a.x, a.y, a.z, a.w, b.x, b.y, b.z, b.w};
    ushort8 o;
#pragma unroll
    for (int j = 0; j < 8; ++j) {
      float q = rintf(v[j] * inv);
      q = fminf(fmaxf(q, -1.f), 1.f);
      o[j] = f2b(q);
    }
    wq[i] = o;
  }
}

// ------- per-token RMSNorm + absmax int8 quant, f32 input (row = 2048) -------
__global__ __launch_bounds__(256) void act_quant_f32_kernel(
    const float* __restrict__ in, unsigned short* __restrict__ out,
    float* __restrict__ fscale) {
  const int token = blockIdx.x, t = threadIdx.x;
  const float4* row = (const float4*)(in + (size_t)token * 2048);
  float4 a = row[2 * t], b = row[2 * t + 1];
  float v[8] = {a.x, a.y, a.z, a.w, b.x, b.y, b.z, b.w};
  float ss = 0.f, am = 0.f;
#pragma unroll
  for (int j = 0; j < 8; ++j) { ss += v[j] * v[j]; am = fmaxf(am, fabsf(v[j])); }
  __shared__ float s1[256], s2[256];
  s1[t] = ss; s2[t] = am; __syncthreads();
  for (int off = 128; off > 0; off >>= 1) {
    if (t < off) { s1[t] += s1[t + off]; s2[t] = fmaxf(s2[t], s2[t + off]); }
    __syncthreads();
  }
  float r = 1.0f / sqrtf(s1[0] * (1.0f / 2048.0f) + 1e-8f);  // rsqrt(mean+RMS_EPS)
  float f = fmaxf(s2[0] * r, 1e-5f);                          // clip(max|xn|,Q_EPS)
  float s = 127.0f / f;
  if (t == 0) fscale[token] = f * (1.0f / 127.0f);            // dequant factor
  ushort8 o;
#pragma unroll
  for (int j = 0; j < 8; ++j) {
    float q = rintf((v[j] * r) * s);
    q = fminf(fmaxf(q, -128.f), 127.f);
    o[j] = f2b(q);  // small ints exact in bf16
  }
  ((ushort8*)(out + (size_t)token * 2048))[t] = o;
}

// ------- per-token RMSNorm + absmax int8 quant, bf16 in-place (row = 8192) ---
__global__ __launch_bounds__(256) void act_quant_bf16_kernel(
    unsigned short* __restrict__ buf, float* __restrict__ fscale) {
  const int token = blockIdx.x, t = threadIdx.x;
  ushort8* row = (ushort8*)(buf + (size_t)token * 8192);
  float v[32];
  float ss = 0.f, am = 0.f;
#pragma unroll
  for (int c = 0; c < 4; ++c) {
    ushort8 u = row[c * 256 + t];
#pragma unroll
    for (int j = 0; j < 8; ++j) {
      float f = b2f(u[j]); v[c * 8 + j] = f;
      ss += f * f; am = fmaxf(am, fabsf(f));
    }
  }
  __shared__ float s1[256], s2[256];
  s1[t] = ss; s2[t] = am; __syncthreads();
  for (int off = 128; off > 0; off >>= 1) {
    if (t < off) { s1[t] += s1[t + off]; s2[t] = fmaxf(s2[t], s2[t + off]); }
    __syncthreads();
  }
  float r = 1.0f / sqrtf(s1[0] * (1.0f / 8192.0f) + 1e-8f);
  float f = fmaxf(s2[0] * r, 1e-5f);
  float s = 127.0f / f;
  if (t == 0) fscale[token] = f * (1.0f / 127.0f);
#pragma unroll
  for (int c = 0; c < 4; ++c) {
    ushort8 o;
#pragma unroll
    for (int j = 0; j < 8; ++j) {
      float q = rintf((v[c * 8 + j] * r) * s);
      q = fminf(fmaxf(q, -128.f), 127.f);
      o[j] = f2b(q);
    }
    row[c * 256 + t] = o;
  }
}

// ---------------- GEMM1: z = silu(Xq@WgT[:I]) * (Xq@WgT[I:]) ----------------
// block: 128 tokens x 64 cols, both halves (gate at n0, value at I+n0).
__global__ __launch_bounds__(256) void gemm1_kernel(
    const unsigned short* __restrict__ A,  // xq [8192,2048] bf16 int
    const unsigned short* __restrict__ B,  // wgq [16384,2048] bf16 ternary
    const float* __restrict__ f1, const float* __restrict__ cgp,
    unsigned short* __restrict__ Z) {      // z bf16 [8192,8192]
  constexpr int K = 2048, I = 8192;
  __shared__ __align__(16) unsigned short As[128 * 64];
  __shared__ __align__(16) unsigned short Bs[128 * 64];  // rows 0..63 gate, 64..127 value
  const int t0 = blockIdx.y * 128, n0 = blockIdx.x * 64;
  const int tid = threadIdx.x, w = tid >> 6, l = tid & 63;
  const int wm = (w >> 1) * 64, wn = (w & 1) * 32;
  const int lr = l >> 3, lc = (l & 7) * 8;
  floatx4 ag[4][2], av[4][2];
#pragma unroll
  for (int i = 0; i < 4; ++i)
#pragma unroll
    for (int j = 0; j < 2; ++j) { ag[i][j] = {0.f,0.f,0.f,0.f}; av[i][j] = {0.f,0.f,0.f,0.f}; }

  const unsigned short* Ap = A + (size_t)(t0 + w * 8 + lr) * K + lc;

  for (int k0 = 0; k0 < K; k0 += 64) {
    __syncthreads();
#pragma unroll
    for (int r = 0; r < 4; ++r) {
      int base = r * 32 + w * 8;  // LDS rows this wave stages
      glds16(Ap + (size_t)r * 32 * K + k0, &As[base * 64]);
      int grow = (base < 64) ? (n0 + base) : (I + n0 + base - 64);
      glds16(B + (size_t)(grow + lr) * K + k0 + lc, &Bs[base * 64]);
    }
    __syncthreads();  // compiler drains vmcnt before barrier
#pragma unroll
    for (int kk = 0; kk < 2; ++kk) {
      short8 af[4], bg[2], bv[2];
#pragma unroll
      for (int i = 0; i < 4; ++i)
        af[i] = *(const short8*)&As[(wm + i * 16 + (l & 15)) * 64 + kk * 32 + (l >> 4) * 8];
#pragma unroll
      for (int j = 0; j < 2; ++j) {
        bg[j] = *(const short8*)&Bs[(wn + j * 16 + (l & 15)) * 64 + kk * 32 + (l >> 4) * 8];
        bv[j] = *(const short8*)&Bs[(64 + wn + j * 16 + (l & 15)) * 64 + kk * 32 + (l >> 4) * 8];
      }
#pragma unroll
      for (int i = 0; i < 4; ++i)
#pragma unroll
        for (int j = 0; j < 2; ++j) {
          ag[i][j] = __builtin_amdgcn_mfma_f32_16x16x32_bf16(af[i], bg[j], ag[i][j], 0, 0, 0);
          av[i][j] = __builtin_amdgcn_mfma_f32_16x16x32_bf16(af[i], bv[j], av[i][j], 0, 0, 0);
        }
    }
  }
  float cg = *cgp;
#pragma unroll
  for (int i = 0; i < 4; ++i)
#pragma unroll
    for (int rr = 0; rr < 4; ++rr) {
      int m = wm + i * 16 + (l >> 4) * 4 + rr;
      float fs = f1[t0 + m] * cg;
#pragma unroll
      for (int j = 0; j < 2; ++j) {
        int n = wn + j * 16 + (l & 15);
        float g = ag[i][j][rr] * fs, vv = av[i][j][rr] * fs;
        float z = g / (1.0f + __expf(-g)) * vv;  // silu(g)*v
        Z[(size_t)(t0 + m) * I + n0 + n] = f2b(z);
      }
    }
}

// ---------------- GEMM2: out = (Zq @ WdT) * f2 * cd  (f32 output) ----------
__global__ __launch_bounds__(256) void gemm2_kernel(
    const unsigned short* __restrict__ A,  // zq [8192,8192] bf16 int
    const unsigned short* __restrict__ B,  // wdq [2048,8192] bf16 ternary
    const float* __restrict__ f2, const float* __restrict__ cdp,
    float* __restrict__ out) {             // [8192,2048] f32
  constexpr int K = 8192, N = 2048;
  __shared__ __align__(16) unsigned short As[128 * 64];
  __shared__ __align__(16) unsigned short Bs[128 * 64];
  const int t0 = blockIdx.y * 128, n0 = blockIdx.x * 128;
  const int tid = threadIdx.x, w = tid >> 6, l = tid & 63;
  const int wm = (w >> 1) * 64, wn = (w & 1) * 64;
  const int lr = l >> 3, lc = (l & 7) * 8;
  floatx4 acc[4][4];
#pragma unroll
  for (int i = 0; i < 4; ++i)
#pragma unroll
    for (int j = 0; j < 4; ++j) acc[i][j] = {0.f,0.f,0.f,0.f};

  const unsigned short* Ap = A + (size_t)(t0 + w * 8 + lr) * K + lc;
  const unsigned short* Bp = B + (size_t)(n0 + w * 8 + lr) * K + lc;

  for (int k0 = 0; k0 < K; k0 += 64) {
    __syncthreads();
#pragma unroll
    for (int r = 0; r < 4; ++r) {
      int base = r * 32 + w * 8;
      glds16(Ap + (size_t)r * 32 * K + k0, &As[base * 64]);
      glds16(Bp + (size_t)r * 32 * K + k0, &Bs[base * 64]);
    }
    __syncthreads();
#pragma unroll
    for (int kk = 0; kk < 2; ++kk) {
      short8 af[4], bf[4];
#pragma unroll
      for (int i = 0; i < 4; ++i) {
        af[i] = *(const short8*)&As[(wm + i * 16 + (l & 15)) * 64 + kk * 32 + (l >> 4) * 8];
        bf[i] = *(const short8*)&Bs[(wn + i * 16 + (l & 15)) * 64 + kk * 32 + (l >> 4) * 8];
      }
#pragma unroll
      for (int i = 0; i < 4; ++i)
#pragma unroll
        for (int j = 0; j < 4; ++j)
          acc[i][j] = __builtin_amdgcn_mfma_f32_16x16x32_bf16(af[i], bf[j], acc[i][j], 0, 0, 0);
    }
  }
  float cd = *cdp;
#pragma unroll
  for (int i = 0; i < 4; ++i)
#pragma unroll
    for (int rr = 0; rr < 4; ++rr) {
      int m = wm + i * 16 + (l >> 4) * 4 + rr;
      float fs = f2[t0 + m] * cd;
#pragma unroll
      for (int j = 0; j < 4; ++j) {
        int n = wn + j * 16 + (l & 15);
        out[(size_t)(t0 + m) * N + n0 + n] = acc[i][j][rr] * fs;
      }
    }
}

extern "C" void kernel_launch(void* const* d_in, const int* in_sizes, int n_in,
                              void* d_out, int out_size, void* d_ws, size_t ws_size,
                              hipStream_t stream) {
  const float* x  = (const float*)d_in[0];  // [8192,2048] f32
  const float* wg = (const float*)d_in[1];  // [16384,2048] f32
  const float* wd = (const float*)d_in[2];  // [2048,8192] f32
  float* out = (float*)d_out;               // [8192,2048] f32

  // workspace layout (~268.6 MB)
  char* ws = (char*)d_ws;
  unsigned short* wgq = (unsigned short*)(ws);                  //  67,108,864 B
  unsigned short* wdq = (unsigned short*)(ws + 67108864);       //  33,554,432 B
  unsigned short* xq  = (unsigned short*)(ws + 100663296);      //  33,554,432 B
  unsigned short* z   = (unsigned short*)(ws + 134217728);      // 134,217,728 B
  float* f1     = (float*)(ws + 268435456);                     //      32,768 B
  float* f2     = (float*)(ws + 268468224);                     //      32,768 B
  float* pf     = (float*)(ws + 268500992);                     //       8,192 B
  float* scales = (float*)(ws + 268509184);                     //          16 B

  // 1) global mean(|w|) for both weight matrices (deterministic, no atomics)
  reduce_abs_kernel<<<1024, 256, 0, stream>>>((const float4*)wg, pf, 8388608);
  reduce_abs_kernel<<<1024, 256, 0, stream>>>((const float4*)wd, pf + 1024, 4194304);
  finalize_kernel<<<1, 256, 0, stream>>>(pf, scales);

  // 2) ternarize weights, int8-quantize activations
  quant_weight_kernel<<<2048, 256, 0, stream>>>((const float4*)wg, (ushort8*)wgq, scales + 2, 4194304);
  quant_weight_kernel<<<1024, 256, 0, stream>>>((const float4*)wd, (ushort8*)wdq, scales + 3, 2097152);
  act_quant_f32_kernel<<<8192, 256, 0, stream>>>(x, xq, f1);

  // 3) GEMM1 fused with dequant + silu*v -> z (bf16)
  gemm1_kernel<<<dim3(128, 64), 256, 0, stream>>>(xq, wgq, f1, scales, z);

  // 4) quantize z in-place
  act_quant_bf16_kernel<<<8192, 256, 0, stream>>>(z, f2);

  // 5) GEMM2 fused with dequant -> out (f32)
  gemm2_kernel<<<dim3(16, 64), 256, 0, stream>>>(z, wdq, f2, scales + 1, out);
}

// Round 3
// 1085.330 us; speedup vs baseline: 1.4694x; 1.4694x over previous
//
#include <hip/hip_runtime.h>

// HGRN BitMLP (all I/O float32):
//   x[8192,2048] -> bitlinear(w_gate[16384,2048]) -> silu(gate)*v
//   -> bitlinear(w_down[2048,8192]) -> out[8192,2048]
// Int8 activations x ternary weights -> mfma_i32_16x16x64_i8 (exact integer
// arithmetic, 2x bf16 rate). LDS tiles stored in fragment order so all
// ds_read_b128 are lane-sequential (zero bank conflicts).

using char8  = __attribute__((ext_vector_type(8))) signed char;
using int4v  = __attribute__((ext_vector_type(4))) int;
using half8  = __attribute__((ext_vector_type(8))) _Float16;

// async global->LDS, 16B per lane; LDS dest = wave-uniform base + lane*16
__device__ __forceinline__ void glds16(const void* g, void* l) {
  __builtin_amdgcn_global_load_lds((const __attribute__((address_space(1))) void*)g,
                                   (__attribute__((address_space(3))) void*)l, 16, 0, 0);
}

// ---------------- deterministic sum(|w|) reduction (f32 input) --------------
__global__ __launch_bounds__(256) void reduce_abs_kernel(
    const float4* __restrict__ w, float* __restrict__ partials, int n4) {
  int t = threadIdx.x;
  int gid = blockIdx.x * 256 + t;
  int stride = gridDim.x * 256;
  float s = 0.f;
  for (int i = gid; i < n4; i += stride) {
    float4 u = w[i];
    s += fabsf(u.x) + fabsf(u.y) + fabsf(u.z) + fabsf(u.w);
  }
  __shared__ float sm[256];
  sm[t] = s; __syncthreads();
  for (int off = 128; off > 0; off >>= 1) {
    if (t < off) sm[t] += sm[t + off];
    __syncthreads();
  }
  if (t == 0) partials[blockIdx.x] = sm[0];
}

__global__ __launch_bounds__(256) void finalize_kernel(
    const float* __restrict__ pf, float* __restrict__ scales) {
  __shared__ float sm[256];
  int t = threadIdx.x;
  float s = pf[t] + pf[t + 256] + pf[t + 512] + pf[t + 768];
  sm[t] = s; __syncthreads();
  for (int off = 128; off > 0; off >>= 1) {
    if (t < off) sm[t] += sm[t + off];
    __syncthreads();
  }
  if (t == 0) {  // w_gate: 16384*2048 elements
    float c = fmaxf(sm[0] / 33554432.0f, 1e-5f);
    scales[0] = c; scales[2] = 1.0f / c;
  }
  __syncthreads();
  s = pf[1024 + t] + pf[1280 + t] + pf[1536 + t] + pf[1792 + t];
  sm[t] = s; __syncthreads();
  for (int off = 128; off > 0; off >>= 1) {
    if (t < off) sm[t] += sm[t + off];
    __syncthreads();
  }
  if (t == 0) {  // w_down: 2048*8192 elements
    float c = fmaxf(sm[0] / 16777216.0f, 1e-5f);
    scales[1] = c; scales[3] = 1.0f / c;
  }
}

// ------- ternary weight quant: f32 in -> {-1,0,1} int8 --------
__global__ __launch_bounds__(256) void quant_weight_kernel(
    const float4* __restrict__ w, char8* __restrict__ wq,
    const float* __restrict__ invp, int n8) {
  float inv = *invp;  // 1/clip(mean|w|,1e-5)
  int stride = gridDim.x * 256;
  for (int i = blockIdx.x * 256 + threadIdx.x; i < n8; i += stride) {
    float4 a = w[2 * i], b = w[2 * i + 1];
    float v[8] = {a.x, a.y, a.z, a.w, b.x, b.y, b.z, b.w};
    char8 o;
#pragma unroll
    for (int j = 0; j < 8; ++j) {
      float q = rintf(v[j] * inv);
      q = fminf(fmaxf(q, -1.f), 1.f);
      o[j] = (signed char)(int)q;
    }
    wq[i] = o;
  }
}

// ------- per-token RMSNorm + absmax int8 quant, f32 input (row = 2048) -------
__global__ __launch_bounds__(256) void act_quant_f32_kernel(
    const float* __restrict__ in, signed char* __restrict__ out,
    float* __restrict__ fscale) {
  const int token = blockIdx.x, t = threadIdx.x;
  const float4* row = (const float4*)(in + (size_t)token * 2048);
  float4 a = row[2 * t], b = row[2 * t + 1];
  float v[8] = {a.x, a.y, a.z, a.w, b.x, b.y, b.z, b.w};
  float ss = 0.f, am = 0.f;
#pragma unroll
  for (int j = 0; j < 8; ++j) { ss += v[j] * v[j]; am = fmaxf(am, fabsf(v[j])); }
  __shared__ float s1[256], s2[256];
  s1[t] = ss; s2[t] = am; __syncthreads();
  for (int off = 128; off > 0; off >>= 1) {
    if (t < off) { s1[t] += s1[t + off]; s2[t] = fmaxf(s2[t], s2[t + off]); }
    __syncthreads();
  }
  float r = 1.0f / sqrtf(s1[0] * (1.0f / 2048.0f) + 1e-8f);  // rsqrt(mean+RMS_EPS)
  float f = fmaxf(s2[0] * r, 1e-5f);                          // clip(max|xn|,Q_EPS)
  float s = 127.0f / f;
  if (t == 0) fscale[token] = f * (1.0f / 127.0f);            // dequant factor
  char8 o;
#pragma unroll
  for (int j = 0; j < 8; ++j) {
    float q = rintf((v[j] * r) * s);
    q = fminf(fmaxf(q, -128.f), 127.f);
    o[j] = (signed char)(int)q;
  }
  ((char8*)(out + (size_t)token * 2048))[t] = o;
}

// ------- per-token RMSNorm + absmax int8 quant, fp16 input (row = 8192) -----
__global__ __launch_bounds__(256) void act_quant_h_kernel(
    const _Float16* __restrict__ in, signed char* __restrict__ out,
    float* __restrict__ fscale) {
  const int token = blockIdx.x, t = threadIdx.x;
  const half8* row = (const half8*)(in + (size_t)token * 8192);
  float v[32];
  float ss = 0.f, am = 0.f;
#pragma unroll
  for (int c = 0; c < 4; ++c) {
    half8 u = row[c * 256 + t];
#pragma unroll
    for (int j = 0; j < 8; ++j) {
      float f = (float)u[j]; v[c * 8 + j] = f;
      ss += f * f; am = fmaxf(am, fabsf(f));
    }
  }
  __shared__ float s1[256], s2[256];
  s1[t] = ss; s2[t] = am; __syncthreads();
  for (int off = 128; off > 0; off >>= 1) {
    if (t < off) { s1[t] += s1[t + off]; s2[t] = fmaxf(s2[t], s2[t + off]); }
    __syncthreads();
  }
  float r = 1.0f / sqrtf(s1[0] * (1.0f / 8192.0f) + 1e-8f);
  float f = fmaxf(s2[0] * r, 1e-5f);
  float s = 127.0f / f;
  if (t == 0) fscale[token] = f * (1.0f / 127.0f);
#pragma unroll
  for (int c = 0; c < 4; ++c) {
    char8 o;
#pragma unroll
    for (int j = 0; j < 8; ++j) {
      float q = rintf((v[c * 8 + j] * r) * s);
      q = fminf(fmaxf(q, -128.f), 127.f);
      o[j] = (signed char)(int)q;
    }
    ((char8*)(out + (size_t)token * 8192))[c * 256 + t] = o;
  }
}

// ---------------- GEMM1: z = silu(Xq@WgT[:I]) * (Xq@WgT[I:]) ----------------
// block: 128 tokens x 64 z-cols (gate rows n0.., value rows I+n0..).
// LDS fragment-order slabs: unit u=(s,kk) is 1024B; slot l holds
// row s*16+(l&15), bytes kk*64+(l>>4)*16 .. +15  ->  frag read = base + l*16.
__global__ __launch_bounds__(256) void gemm1_kernel(
    const signed char* __restrict__ A,  // xq [8192,2048] i8
    const signed char* __restrict__ B,  // wgq [16384,2048] i8 ternary
    const float* __restrict__ f1, const float* __restrict__ cgp,
    _Float16* __restrict__ Z) {         // z fp16 [8192,8192]
  constexpr int K = 2048, I = 8192;
  __shared__ __align__(16) signed char As[16384];  // 8 slabs x 2 kk x 1024B
  __shared__ __align__(16) signed char Bs[16384];  // slabs 0-3 gate, 4-7 value
  const int t0 = blockIdx.y * 128, n0 = blockIdx.x * 64;
  const int tid = threadIdx.x, w = tid >> 6, l = tid & 63;
  const int wm = (w >> 1) * 64, wn = (w & 1) * 32;
  const int lrow = l & 15, lchunk = (l >> 4) * 16;

  int4v ag[4][2], av[4][2];
#pragma unroll
  for (int i = 0; i < 4; ++i)
#pragma unroll
    for (int j = 0; j < 2; ++j) { ag[i][j] = {0,0,0,0}; av[i][j] = {0,0,0,0}; }

  const signed char* aptr[4];
  const signed char* bptr[4];
  int ldsu[4];
#pragma unroll
  for (int r = 0; r < 4; ++r) {
    int u = w * 4 + r, s = u >> 1, kk = u & 1;
    aptr[r] = A + (size_t)(t0 + s * 16 + lrow) * K + kk * 64 + lchunk;
    int grow = (s < 4) ? (n0 + s * 16 + lrow) : (I + n0 + (s - 4) * 16 + lrow);
    bptr[r] = B + (size_t)grow * K + kk * 64 + lchunk;
    ldsu[r] = u * 1024;
  }

  for (int k0 = 0; k0 < K; k0 += 128) {
    __syncthreads();
#pragma unroll
    for (int r = 0; r < 4; ++r) {
      glds16(aptr[r] + k0, &As[ldsu[r]]);
      glds16(bptr[r] + k0, &Bs[ldsu[r]]);
    }
    __syncthreads();
#pragma unroll
    for (int kk = 0; kk < 2; ++kk) {
      int4v af[4], bg[2], bv[2];
#pragma unroll
      for (int i = 0; i < 4; ++i)
        af[i] = *(const int4v*)&As[(((wm >> 4) + i) * 2 + kk) * 1024 + l * 16];
#pragma unroll
      for (int j = 0; j < 2; ++j) {
        bg[j] = *(const int4v*)&Bs[(((wn >> 4) + j) * 2 + kk) * 1024 + l * 16];
        bv[j] = *(const int4v*)&Bs[(((wn >> 4) + j + 4) * 2 + kk) * 1024 + l * 16];
      }
#pragma unroll
      for (int i = 0; i < 4; ++i)
#pragma unroll
        for (int j = 0; j < 2; ++j) {
          ag[i][j] = __builtin_amdgcn_mfma_i32_16x16x64_i8(af[i], bg[j], ag[i][j], 0, 0, 0);
          av[i][j] = __builtin_amdgcn_mfma_i32_16x16x64_i8(af[i], bv[j], av[i][j], 0, 0, 0);
        }
    }
  }
  float cg = *cgp;
#pragma unroll
  for (int i = 0; i < 4; ++i)
#pragma unroll
    for (int rr = 0; rr < 4; ++rr) {
      int m = wm + i * 16 + (l >> 4) * 4 + rr;
      float fs = f1[t0 + m] * cg;
#pragma unroll
      for (int j = 0; j < 2; ++j) {
        int n = wn + j * 16 + (l & 15);
        float g = (float)ag[i][j][rr] * fs, vv = (float)av[i][j][rr] * fs;
        float z = g / (1.0f + __expf(-g)) * vv;  // silu(g)*v
        Z[(size_t)(t0 + m) * I + n0 + n] = (_Float16)z;
      }
    }
}

// ---------------- GEMM2: out = (Zq @ WdT) * f2 * cd  (f32 output) ----------
__global__ __launch_bounds__(256) void gemm2_kernel(
    const signed char* __restrict__ A,  // zq [8192,8192] i8
    const signed char* __restrict__ B,  // wdq [2048,8192] i8 ternary
    const float* __restrict__ f2, const float* __restrict__ cdp,
    float* __restrict__ out) {          // [8192,2048] f32
  constexpr int K = 8192, N = 2048;
  __shared__ __align__(16) signed char As[16384];
  __shared__ __align__(16) signed char Bs[16384];
  const int t0 = blockIdx.y * 128, n0 = blockIdx.x * 128;
  const int tid = threadIdx.x, w = tid >> 6, l = tid & 63;
  const int wm = (w >> 1) * 64, wn = (w & 1) * 64;
  const int lrow = l & 15, lchunk = (l >> 4) * 16;

  int4v acc[4][4];
#pragma unroll
  for (int i = 0; i < 4; ++i)
#pragma unroll
    for (int j = 0; j < 4; ++j) acc[i][j] = {0,0,0,0};

  const signed char* aptr[4];
  const signed char* bptr[4];
  int ldsu[4];
#pragma unroll
  for (int r = 0; r < 4; ++r) {
    int u = w * 4 + r, s = u >> 1, kk = u & 1;
    aptr[r] = A + (size_t)(t0 + s * 16 + lrow) * K + kk * 64 + lchunk;
    bptr[r] = B + (size_t)(n0 + s * 16 + lrow) * K + kk * 64 + lchunk;
    ldsu[r] = u * 1024;
  }

  for (int k0 = 0; k0 < K; k0 += 128) {
    __syncthreads();
#pragma unroll
    for (int r = 0; r < 4; ++r) {
      glds16(aptr[r] + k0, &As[ldsu[r]]);
      glds16(bptr[r] + k0, &Bs[ldsu[r]]);
    }
    __syncthreads();
#pragma unroll
    for (int kk = 0; kk < 2; ++kk) {
      int4v af[4], bf[4];
#pragma unroll
      for (int i = 0; i < 4; ++i) {
        af[i] = *(const int4v*)&As[(((wm >> 4) + i) * 2 + kk) * 1024 + l * 16];
        bf[i] = *(const int4v*)&Bs[(((wn >> 4) + i) * 2 + kk) * 1024 + l * 16];
      }
#pragma unroll
      for (int i = 0; i < 4; ++i)
#pragma unroll
        for (int j = 0; j < 4; ++j)
          acc[i][j] = __builtin_amdgcn_mfma_i32_16x16x64_i8(af[i], bf[j], acc[i][j], 0, 0, 0);
    }
  }
  float cd = *cdp;
#pragma unroll
  for (int i = 0; i < 4; ++i)
#pragma unroll
    for (int rr = 0; rr < 4; ++rr) {
      int m = wm + i * 16 + (l >> 4) * 4 + rr;
      float fs = f2[t0 + m] * cd;
#pragma unroll
      for (int j = 0; j < 4; ++j) {
        int n = wn + j * 16 + (l & 15);
        out[(size_t)(t0 + m) * N + n0 + n] = (float)acc[i][j][rr] * fs;
      }
    }
}

extern "C" void kernel_launch(void* const* d_in, const int* in_sizes, int n_in,
                              void* d_out, int out_size, void* d_ws, size_t ws_size,
                              hipStream_t stream) {
  const float* x  = (const float*)d_in[0];  // [8192,2048] f32
  const float* wg = (const float*)d_in[1];  // [16384,2048] f32
  const float* wd = (const float*)d_in[2];  // [2048,8192] f32
  float* out = (float*)d_out;               // [8192,2048] f32

  // workspace layout (~268.5 MB)
  char* ws = (char*)d_ws;
  signed char* wgq = (signed char*)(ws);                 //  33,554,432 B
  signed char* wdq = (signed char*)(ws + 33554432);      //  16,777,216 B
  signed char* xq  = (signed char*)(ws + 50331648);      //  16,777,216 B
  signed char* zq  = (signed char*)(ws + 67108864);      //  67,108,864 B
  _Float16*    z   = (_Float16*)  (ws + 134217728);      // 134,217,728 B
  float* f1     = (float*)(ws + 268435456);              //      32,768 B
  float* f2     = (float*)(ws + 268468224);              //      32,768 B
  float* pf     = (float*)(ws + 268500992);              //       8,192 B
  float* scales = (float*)(ws + 268509184);              //          16 B

  // 1) global mean(|w|) for both weight matrices (deterministic, no atomics)
  reduce_abs_kernel<<<1024, 256, 0, stream>>>((const float4*)wg, pf, 8388608);
  reduce_abs_kernel<<<1024, 256, 0, stream>>>((const float4*)wd, pf + 1024, 4194304);
  finalize_kernel<<<1, 256, 0, stream>>>(pf, scales);

  // 2) ternarize weights, int8-quantize activations
  quant_weight_kernel<<<2048, 256, 0, stream>>>((const float4*)wg, (char8*)wgq, scales + 2, 4194304);
  quant_weight_kernel<<<1024, 256, 0, stream>>>((const float4*)wd, (char8*)wdq, scales + 3, 2097152);
  act_quant_f32_kernel<<<8192, 256, 0, stream>>>(x, xq, f1);

  // 3) GEMM1 (i8) fused with dequant + silu*v -> z (fp16)
  gemm1_kernel<<<dim3(128, 64), 256, 0, stream>>>(xq, wgq, f1, scales, z);

  // 4) quantize z -> zq (i8) + f2
  act_quant_h_kernel<<<8192, 256, 0, stream>>>(z, zq, f2);

  // 5) GEMM2 (i8) fused with dequant -> out (f32)
  gemm2_kernel<<<dim3(16, 64), 256, 0, stream>>>(zq, wdq, f2, scales + 1, out);
}